// Round 23
// baseline (101.869 us; speedup 1.0000x reference)
//
#include <hip/hip_runtime.h>

#define NB  32
#define IDF 768
#define SLN 128
#define QLN 1024
#define NT  24    // IDF/32 (proj windows)
#define NT2 12    // IDF/64 (qkpv windows)

typedef _Float16 v8hf __attribute__((ext_vector_type(8)));
typedef _Float16 v4hf __attribute__((ext_vector_type(4)));
typedef float    v4f  __attribute__((ext_vector_type(4)));

#define MFMAH __builtin_amdgcn_mfma_f32_16x16x32_f16

__device__ __forceinline__ void gload16(const void* g, void* l) {
  __builtin_amdgcn_global_load_lds(
      (const __attribute__((address_space(1))) void*)g,
      (__attribute__((address_space(3))) void*)l, 16, 0, 0);
}

__device__ __forceinline__ void lbar() {
  asm volatile("s_waitcnt lgkmcnt(0)" ::: "memory");
  __builtin_amdgcn_sched_barrier(0);
  __builtin_amdgcn_s_barrier();
  __builtin_amdgcn_sched_barrier(0);
}

// -----------------------------------------------------------------------------
// K0 prep: blocks 0..575: W f32 -> Wf fp16; blocks 576..959: transpose ctx
// [b][c][s] f32 -> cTf [b][s][c] fp16.  (unchanged)
// -----------------------------------------------------------------------------
__global__ __launch_bounds__(256) void prep_k(const float* __restrict__ W,
                                              const float* __restrict__ ctx,
                                              _Float16* __restrict__ Wf,
                                              _Float16* __restrict__ cTf) {
  const int bid = blockIdx.x, t = threadIdx.x;
  __shared__ float tl[64][133];
  if (bid < 576) {
    int idx = bid * 1024 + t * 4;
    float4 v = *(const float4*)(W + idx);
    v4hf h;
    h[0] = (_Float16)v.x;
    h[1] = (_Float16)v.y;
    h[2] = (_Float16)v.z;
    h[3] = (_Float16)v.w;
    *(v4hf*)(Wf + idx) = h;
    return;
  }
  const int cid = bid - 576;
  const int b = cid / 12, c0 = (cid % 12) * 64;
#pragma unroll
  for (int j = 0; j < 8; ++j) {
    int u = j * 256 + t;
    int c = u >> 5, s4 = (u & 31) * 4;
    *(float4*)&tl[c][s4] =
        *(const float4*)(ctx + ((size_t)b * IDF + c0 + c) * SLN + s4);
  }
  __syncthreads();
#pragma unroll
  for (int j = 0; j < 8; ++j) {
    int u = j * 256 + t;
    int s = u >> 4, c4 = (u & 15) * 4;
    v4hf h;
#pragma unroll
    for (int e = 0; e < 4; ++e) h[e] = (_Float16)tl[c4 + e][s];
    *(v4hf*)(cTf + ((size_t)b * SLN + s) * IDF + c0 + c4) = h;
  }
}

// -----------------------------------------------------------------------------
// K1 proj: unchanged (fp16, known-good).
// -----------------------------------------------------------------------------
__global__ __launch_bounds__(256) void proj_k(const _Float16* __restrict__ cTf,
                                              const _Float16* __restrict__ Wf,
                                              _Float16* __restrict__ STf,
                                              _Float16* __restrict__ Shvf) {
  const int b = blockIdx.y, o0 = blockIdx.x * 32;
  const int t = threadIdx.x, w = t >> 6, lane = t & 63;
  const int lr = lane & 15, lg = lane >> 4;
  const int ws = w >> 1, wq = w & 1;
  __shared__ _Float16 AL[128][32];

  v4f acc[4];
#pragma unroll
  for (int fr = 0; fr < 4; ++fr) acc[fr] = (v4f){0.f, 0.f, 0.f, 0.f};

  const int ra = t >> 1, ca0 = (t & 1) * 2;
  const int swA = (ra >> 1) & 3;
  const int pa0 = (ca0 ^ swA) * 8, pa1 = ((ca0 + 1) ^ swA) * 8;
  const _Float16* pA = cTf + ((size_t)b * SLN + ra) * IDF + ca0 * 8;
  const size_t wOff = (size_t)(o0 + wq * 16 + lr) * IDF + lg * 8;

  uint4 aA0, aA1, bA0, bA1;
  v8hf bhc, bhn;
  aA0 = *(const uint4*)(pA);
  aA1 = *(const uint4*)(pA + 8);
  bA0 = *(const uint4*)(pA + 32);
  bA1 = *(const uint4*)(pA + 40);
  bhc = *(const v8hf*)(Wf + wOff);

#define PROJ_BODY(S0, S1, IT)                                                  \
  {                                                                            \
    lbar();                                                                    \
    *(uint4*)&AL[ra][pa0] = S0;                                                \
    *(uint4*)&AL[ra][pa1] = S1;                                                \
    if ((IT) + 2 < NT) {                                                       \
      S0 = *(const uint4*)(pA + ((IT) + 2) * 32);                              \
      S1 = *(const uint4*)(pA + ((IT) + 2) * 32 + 8);                          \
    }                                                                          \
    if ((IT) + 1 < NT) {                                                       \
      bhn = *(const v8hf*)(Wf + wOff + ((IT) + 1) * 32);                       \
    }                                                                          \
    lbar();                                                                    \
    _Pragma("unroll") for (int fr = 0; fr < 4; ++fr) {                         \
      const int r = ws * 64 + fr * 16 + lr;                                    \
      const int pp = (lg ^ ((r >> 1) & 3)) * 8;                                \
      v8hf ah = *(const v8hf*)&AL[r][pp];                                      \
      acc[fr] = MFMAH(ah, bhc, acc[fr], 0, 0, 0);                              \
    }                                                                          \
    bhc = bhn;                                                                 \
  }

  for (int it2 = 0; it2 < NT / 2; ++it2) {
    const int itE = it2 * 2;
    PROJ_BODY(aA0, aA1, itE);
    PROJ_BODY(bA0, bA1, itE + 1);
  }
#undef PROJ_BODY

  const int o = o0 + wq * 16 + lr;
#pragma unroll
  for (int fr = 0; fr < 4; ++fr) {
    v4hf hp;
#pragma unroll
    for (int r = 0; r < 4; ++r) {
      int s = ws * 64 + fr * 16 + lg * 4 + r;
      _Float16 h = (_Float16)acc[fr][r];
      STf[((size_t)b * SLN + s) * IDF + o] = h;
      hp[r] = h;
    }
    *(v4hf*)(Shvf + ((size_t)b * IDF + o) * SLN + ws * 64 + fr * 16 + lg * 4) =
        hp;
  }
}

// -----------------------------------------------------------------------------
// K2 qkpv: q-tile 32, grid 1024 = 4 blocks/CU (4 barrier domains, the lever
// the round-16 diag validated). 256 thr, 4 waves: wq = w&1 (one q-frag),
// sh2 = w>>1 (s-half, 4 fr). BK=64, 12 windows, 8 MFMA/wave/window.
// A via gload_lds chunk-XOR c' = c ^ (r&7) presourced (4/wave/window).
// B = input direct-global: tmpB[2][8] transient f32, cvt to packed v8hf set
// AFTER the MFMA cluster (round-22 register diet). vmcnt entry 4, final 0.
// Values bit-identical to round 22. LDS 33.8 KB; PL 8 KB overlays buf0.
// -----------------------------------------------------------------------------
__global__ __launch_bounds__(256, 4) void qkpv_k(const float* __restrict__ input,
                                                 const _Float16* __restrict__ STf,
                                                 const _Float16* __restrict__ Shvf,
                                                 const int* __restrict__ mask,
                                                 float* __restrict__ wc,
                                                 float* __restrict__ attn_out) {
  const int bid = blockIdx.x;
  const int nid = (bid & 7) * 128 + (bid >> 3);  // XCD swizzle, 1024 blocks
  const int b = nid >> 5, q0 = (nid & 31) * 32;
  const int t = threadIdx.x, w = t >> 6, lane = t & 63;
  const int lr = lane & 15, lg = lane >> 4;
  const int wq = w & 1, sh2 = w >> 1;

  // LDS: buf0 @0 (16K [128 r][64 k] fp16 swizzled), buf1 @16384,
  // msk @32768 (512B), redm @33280 (256B), reds @33536 (256B). 33792 B.
  __shared__ __align__(16) char lds[33792];
  float* const msk  = (float*)(lds + 32768);
  float* const redm = (float*)(lds + 33280);
  float* const reds = (float*)(lds + 33536);
  char* const PLb = lds;  // P tile (8 KB) overlays buf0 after QK

  if (t < SLN) msk[t] = -10000.0f * (float)mask[b * SLN + t];

  v4f acc[4];
#pragma unroll
  for (int fr = 0; fr < 4; ++fr) acc[fr] = (v4f){0.f, 0.f, 0.f, 0.f};

  // A staging: wave w stages rows [w*32, w*32+32) x 64 k as 4 gloads.
  const int rA = (lane >> 3);
  const int cpA = lane & 7;
  const _Float16* gA[4];
#pragma unroll
  for (int g = 0; g < 4; ++g) {
    const int row = w * 32 + g * 8 + rA;
    const int c = cpA ^ (row & 7);
    gA[g] = STf + ((size_t)b * SLN + row) * IDF + c * 8;
  }
  const int dA = w * 4096;  // bytes: 32 rows x 128 B

  // B direct-global: lane covers q = q0 + wq*16 + lr; k-steps kk=0,1
  const float* gB = input + (size_t)b * IDF * QLN + q0 + wq * 16 + lr;

  // prologue: A(0) gloads; B(0) load+cvt; A(1) gloads
#pragma unroll
  for (int g = 0; g < 4; ++g) gload16(gA[g], lds + dA + g * 1024);
  v8hf aH[2], bH[2];
  float tmpB[2][8];
#pragma unroll
  for (int kk = 0; kk < 2; ++kk)
#pragma unroll
    for (int e = 0; e < 8; ++e)
      tmpB[kk][e] = gB[(size_t)(kk * 32 + lg * 8 + e) * QLN];
#pragma unroll
  for (int kk = 0; kk < 2; ++kk)
#pragma unroll
    for (int e = 0; e < 8; ++e) aH[kk][e] = (_Float16)tmpB[kk][e];
#pragma unroll
  for (int g = 0; g < 4; ++g) gload16(gA[g] + 64, lds + 16384 + dA + g * 1024);

#define QK_WIN(CUROFF, BC, BN, IT, VMC)                                        \
  {                                                                            \
    asm volatile("s_waitcnt vmcnt(" #VMC ")" ::: "memory");                    \
    __builtin_amdgcn_sched_barrier(0);                                         \
    __builtin_amdgcn_s_barrier();                                              \
    __builtin_amdgcn_sched_barrier(0);                                         \
    if ((IT) + 1 < NT2) {                                                      \
      _Pragma("unroll") for (int kk = 0; kk < 2; ++kk)                         \
          _Pragma("unroll") for (int e = 0; e < 8; ++e)                        \
          tmpB[kk][e] =                                                        \
              gB[(size_t)(((IT) + 1) * 64 + kk * 32 + lg * 8 + e) * QLN];      \
    }                                                                          \
    __builtin_amdgcn_sched_barrier(0);                                         \
    const char* Ab = lds + (CUROFF);                                           \
    __builtin_amdgcn_s_setprio(1);                                             \
    _Pragma("unroll") for (int fr = 0; fr < 4; ++fr) {                         \
      const int r = sh2 * 64 + fr * 16 + lr;                                   \
      _Pragma("unroll") for (int kk = 0; kk < 2; ++kk) {                       \
        const int cc = (kk * 4 + lg) ^ (r & 7);                                \
        v8hf ah = *(const v8hf*)(Ab + r * 128 + cc * 16);                      \
        acc[fr] = MFMAH(ah, BC[kk], acc[fr], 0, 0, 0);                         \
      }                                                                        \
    }                                                                          \
    __builtin_amdgcn_s_setprio(0);                                             \
    __builtin_amdgcn_sched_barrier(0);                                         \
    if ((IT) + 1 < NT2) {                                                      \
      _Pragma("unroll") for (int kk = 0; kk < 2; ++kk)                         \
          _Pragma("unroll") for (int e = 0; e < 8; ++e)                        \
          BN[kk][e] = (_Float16)tmpB[kk][e];                                   \
    }                                                                          \
    asm volatile("s_waitcnt lgkmcnt(0)" ::: "memory");                         \
    __builtin_amdgcn_s_barrier();                                              \
    if ((IT) + 2 < NT2) {                                                      \
      _Pragma("unroll") for (int g = 0; g < 4; ++g)                            \
          gload16(gA[g] + (size_t)((IT) + 2) * 64,                             \
                  lds + (CUROFF) + dA + g * 1024);                             \
    }                                                                          \
  }

  for (int it2 = 0; it2 < 5; ++it2) {
    const int itE = it2 * 2;
    QK_WIN(0, aH, bH, itE, 4);
    QK_WIN(16384, bH, aH, itE + 1, 4);
  }
  QK_WIN(0, aH, bH, 10, 4);
  QK_WIN(16384, bH, aH, 11, 0);
#undef QK_WIN

  // softmax over s=128 for q = q0 + wq*16 + lr; wave owns s-half sh2
  const int qh = wq * 16 + lr;
  float mx = -3.0e38f;
#pragma unroll
  for (int fr = 0; fr < 4; ++fr)
#pragma unroll
    for (int r = 0; r < 4; ++r) {
      acc[fr][r] += msk[sh2 * 64 + fr * 16 + lg * 4 + r];
      mx = fmaxf(mx, acc[fr][r]);
    }
  mx = fmaxf(mx, __shfl_xor(mx, 16));
  mx = fmaxf(mx, __shfl_xor(mx, 32));
  if (lg == 0) redm[sh2 * 32 + qh] = mx;
  __syncthreads();
  mx = fmaxf(redm[qh], redm[32 + qh]);
  float sum = 0.f;
#pragma unroll
  for (int fr = 0; fr < 4; ++fr)
#pragma unroll
    for (int r = 0; r < 4; ++r) {
      float e = __expf(acc[fr][r] - mx);
      acc[fr][r] = e;
      sum += e;
    }
  sum += __shfl_xor(sum, 16);
  sum += __shfl_xor(sum, 32);
  if (lg == 0) reds[sh2 * 32 + qh] = sum;
  __syncthreads();
  const float inv = 1.0f / (reds[qh] + reds[32 + qh]);
  const int q = q0 + qh;
#pragma unroll
  for (int fr = 0; fr < 4; ++fr) {
    v4hf hp;
#pragma unroll
    for (int r = 0; r < 4; ++r) {
      float p = acc[fr][r] * inv;
      attn_out[((size_t)b * SLN + sh2 * 64 + fr * 16 + lg * 4 + r) * QLN + q] = p;
      hp[r] = (_Float16)p;
    }
    const int g = (sh2 * 8 + fr * 2 + (lg >> 1)) ^ lr;
    *(v4hf*)(PLb + qh * 256 + g * 16 + (lg & 1) * 8) = hp;
  }
  __syncthreads();

  // ---- PV: wave -> (qf = w&1, islab = (w>>1)*384, 24 i-frags) ----
  const int qf = w & 1;
  const int islab = (w >> 1) * 384;
  v8hf pav[4];
#pragma unroll
  for (int kt = 0; kt < 4; ++kt) {
    const int g0 = (kt * 4 + lg) ^ lr;
    pav[kt] = *(const v8hf*)(PLb + (qf * 16 + lr) * 256 + g0 * 16);
  }
  const _Float16* pShv = Shvf + ((size_t)b * IDF + islab + lr) * SLN + lg * 8;
  float* pWc = wc + ((size_t)b * IDF + islab + lr) * QLN + q0 + qf * 16 + lg * 4;
#pragma unroll 4
  for (int ifr = 0; ifr < 24; ++ifr) {
    v4f a0 = (v4f){0.f, 0.f, 0.f, 0.f};
#pragma unroll
    for (int kt = 0; kt < 4; ++kt) {
      v8hf bb = *(const v8hf*)(pShv + (size_t)(ifr * 16) * SLN + kt * 32);
      a0 = MFMAH(pav[kt], bb, a0, 0, 0, 0);
    }
    *(float4*)(pWc + (size_t)(ifr * 16) * QLN) =
        make_float4(a0[0], a0[1], a0[2], a0[3]);
  }
}

// -----------------------------------------------------------------------------
extern "C" void kernel_launch(void* const* d_in, const int* in_sizes, int n_in,
                              void* d_out, int out_size, void* d_ws, size_t ws_size,
                              hipStream_t stream) {
  const float* input   = (const float*)d_in[0];
  const float* context = (const float*)d_in[1];
  const int*   mask    = (const int*)d_in[2];
  const float* w_conv  = (const float*)d_in[3];

  float* out      = (float*)d_out;
  float* wc       = out;
  float* attn_out = out + (size_t)NB * IDF * QLN;

  // ws: STf | Shvf = 12,582,912 B (< 29.36 MB OK).
  // Scratch in wc output region (dead before PV): cTf | Wf.
  const size_t SE = (size_t)NB * SLN * IDF;  // 3,145,728
  _Float16* wsb = (_Float16*)d_ws;
  _Float16* STf  = wsb;
  _Float16* Shvf = STf + SE;
  _Float16* scr  = (_Float16*)wc;
  _Float16* cTf  = scr;
  _Float16* Wf   = cTf + SE;

  prep_k<<<960, 256, 0, stream>>>(w_conv, context, Wf, cTf);
  proj_k<<<dim3(24, NB), 256, 0, stream>>>(cTf, Wf, STf, Shvf);
  qkpv_k<<<1024, 256, 0, stream>>>(input, STf, Shvf, mask, wc, attn_out);
}

// Round 24
// 79.325 us; speedup vs baseline: 1.2842x; 1.2842x over previous
//
#include <hip/hip_runtime.h>

#define NB  32
#define IDF 768
#define SLN 128
#define QLN 1024
#define NT2 12    // IDF/64 (BK=64 windows, proj + qkpv)

typedef _Float16 v8hf __attribute__((ext_vector_type(8)));
typedef _Float16 v4hf __attribute__((ext_vector_type(4)));
typedef float    v4f  __attribute__((ext_vector_type(4)));

#define MFMAH __builtin_amdgcn_mfma_f32_16x16x32_f16

__device__ __forceinline__ void gload16(const void* g, void* l) {
  __builtin_amdgcn_global_load_lds(
      (const __attribute__((address_space(1))) void*)g,
      (__attribute__((address_space(3))) void*)l, 16, 0, 0);
}

__device__ __forceinline__ void lbar() {
  asm volatile("s_waitcnt lgkmcnt(0)" ::: "memory");
  __builtin_amdgcn_sched_barrier(0);
  __builtin_amdgcn_s_barrier();
  __builtin_amdgcn_sched_barrier(0);
}

// -----------------------------------------------------------------------------
// K0 prep: blocks 0..575: W f32 -> Wf fp16; blocks 576..959: transpose ctx
// [b][c][s] f32 -> cTf [b][s][c] fp16.  (unchanged, known-good)
// -----------------------------------------------------------------------------
__global__ __launch_bounds__(256) void prep_k(const float* __restrict__ W,
                                              const float* __restrict__ ctx,
                                              _Float16* __restrict__ Wf,
                                              _Float16* __restrict__ cTf) {
  const int bid = blockIdx.x, t = threadIdx.x;
  __shared__ float tl[64][133];
  if (bid < 576) {
    int idx = bid * 1024 + t * 4;
    float4 v = *(const float4*)(W + idx);
    v4hf h;
    h[0] = (_Float16)v.x;
    h[1] = (_Float16)v.y;
    h[2] = (_Float16)v.z;
    h[3] = (_Float16)v.w;
    *(v4hf*)(Wf + idx) = h;
    return;
  }
  const int cid = bid - 576;
  const int b = cid / 12, c0 = (cid % 12) * 64;
#pragma unroll
  for (int j = 0; j < 8; ++j) {
    int u = j * 256 + t;
    int c = u >> 5, s4 = (u & 31) * 4;
    *(float4*)&tl[c][s4] =
        *(const float4*)(ctx + ((size_t)b * IDF + c0 + c) * SLN + s4);
  }
  __syncthreads();
#pragma unroll
  for (int j = 0; j < 8; ++j) {
    int u = j * 256 + t;
    int s = u >> 4, c4 = (u & 15) * 4;
    v4hf h;
#pragma unroll
    for (int e = 0; e < 4; ++e) h[e] = (_Float16)tl[c4 + e][s];
    *(v4hf*)(cTf + ((size_t)b * SLN + s) * IDF + c0 + c4) = h;
  }
}

// -----------------------------------------------------------------------------
// K1 proj: BK=64 -> 12 windows, 8 MFMA/wave/window (was 24 windows x 4).
// Tile 128s x 32o, grid (24,32), 4 waves (ws = w>>1 s-half, wq = w&1 o-16).
// A = cTf reg-staged into PADDED LDS [128][72] fp16 (stride-72 rows: no
// swizzle needed; 16-lane column reads 2-way = free). 4 uint4/thread/window,
// 2-deep named prefetch. B = Wf frags (2 per window) 1-deep from L2.
// k-ascending per-acc MFMA order preserved -> outputs bit-identical.
// -----------------------------------------------------------------------------
__global__ __launch_bounds__(256) void proj_k(const _Float16* __restrict__ cTf,
                                              const _Float16* __restrict__ Wf,
                                              _Float16* __restrict__ STf,
                                              _Float16* __restrict__ Shvf) {
  const int b = blockIdx.y, o0 = blockIdx.x * 32;
  const int t = threadIdx.x, w = t >> 6, lane = t & 63;
  const int lr = lane & 15, lg = lane >> 4;
  const int ws = w >> 1, wq = w & 1;
  __shared__ _Float16 AL[128][72];  // padded stride; 18.4 KB

  v4f acc[4];
#pragma unroll
  for (int fr = 0; fr < 4; ++fr) acc[fr] = (v4f){0.f, 0.f, 0.f, 0.f};

  // staging map: row = t>>1, chunk base (t&1)*4 (4 chunks of 8 fp16)
  const int ra = t >> 1;
  const int cb = (t & 1) * 4;
  const _Float16* pA = cTf + ((size_t)b * SLN + ra) * IDF + cb * 8;
  const size_t wOff = (size_t)(o0 + wq * 16 + lr) * IDF + lg * 8;

  uint4 aS0, aS1, aS2, aS3, bS0, bS1, bS2, bS3;
  v8hf wc0, wc1, wn0, wn1;
  aS0 = *(const uint4*)(pA);
  aS1 = *(const uint4*)(pA + 8);
  aS2 = *(const uint4*)(pA + 16);
  aS3 = *(const uint4*)(pA + 24);
  bS0 = *(const uint4*)(pA + 64);
  bS1 = *(const uint4*)(pA + 72);
  bS2 = *(const uint4*)(pA + 80);
  bS3 = *(const uint4*)(pA + 88);
  wc0 = *(const v8hf*)(Wf + wOff);
  wc1 = *(const v8hf*)(Wf + wOff + 32);

#define PROJ_BODY(S0, S1, S2, S3, IT)                                          \
  {                                                                            \
    lbar();                                                                    \
    *(uint4*)&AL[ra][(cb + 0) * 8] = S0;                                       \
    *(uint4*)&AL[ra][(cb + 1) * 8] = S1;                                       \
    *(uint4*)&AL[ra][(cb + 2) * 8] = S2;                                       \
    *(uint4*)&AL[ra][(cb + 3) * 8] = S3;                                       \
    if ((IT) + 2 < NT2) {                                                      \
      S0 = *(const uint4*)(pA + ((IT) + 2) * 64);                              \
      S1 = *(const uint4*)(pA + ((IT) + 2) * 64 + 8);                          \
      S2 = *(const uint4*)(pA + ((IT) + 2) * 64 + 16);                         \
      S3 = *(const uint4*)(pA + ((IT) + 2) * 64 + 24);                         \
    }                                                                          \
    if ((IT) + 1 < NT2) {                                                      \
      wn0 = *(const v8hf*)(Wf + wOff + ((IT) + 1) * 64);                       \
      wn1 = *(const v8hf*)(Wf + wOff + ((IT) + 1) * 64 + 32);                  \
    }                                                                          \
    lbar();                                                                    \
    _Pragma("unroll") for (int fr = 0; fr < 4; ++fr) {                         \
      const int r = ws * 64 + fr * 16 + lr;                                    \
      v8hf ah0 = *(const v8hf*)&AL[r][lg * 8];                                 \
      acc[fr] = MFMAH(ah0, wc0, acc[fr], 0, 0, 0);                             \
      v8hf ah1 = *(const v8hf*)&AL[r][32 + lg * 8];                            \
      acc[fr] = MFMAH(ah1, wc1, acc[fr], 0, 0, 0);                             \
    }                                                                          \
    wc0 = wn0;                                                                 \
    wc1 = wn1;                                                                 \
  }

  for (int it2 = 0; it2 < NT2 / 2; ++it2) {
    const int itE = it2 * 2;
    PROJ_BODY(aS0, aS1, aS2, aS3, itE);
    PROJ_BODY(bS0, bS1, bS2, bS3, itE + 1);
  }
#undef PROJ_BODY

  const int o = o0 + wq * 16 + lr;
#pragma unroll
  for (int fr = 0; fr < 4; ++fr) {
    v4hf hp;
#pragma unroll
    for (int r = 0; r < 4; ++r) {
      int s = ws * 64 + fr * 16 + lg * 4 + r;
      _Float16 h = (_Float16)acc[fr][r];
      STf[((size_t)b * SLN + s) * IDF + o] = h;
      hp[r] = h;
    }
    *(v4hf*)(Shvf + ((size_t)b * IDF + o) * SLN + ws * 64 + fr * 16 + lg * 4) =
        hp;
  }
}

// -----------------------------------------------------------------------------
// K2 qkpv: EXACT round-22 kernel (best known: 81.2 us total). BK=64, 12
// windows, 16 MFMA/wave/window; 256 thr, 4 waves (wqp = w&1, sh2 = w>>1).
// Register-diet B prefetch (transient f32 tmpB, cvt after MFMA cluster).
// -----------------------------------------------------------------------------
__global__ __launch_bounds__(256, 4) void qkpv_k(const float* __restrict__ input,
                                                 const _Float16* __restrict__ STf,
                                                 const _Float16* __restrict__ Shvf,
                                                 const int* __restrict__ mask,
                                                 float* __restrict__ wc,
                                                 float* __restrict__ attn_out) {
  const int bid = blockIdx.x;
  const int nid = (bid & 7) * 64 + (bid >> 3);  // XCD swizzle, 512 blocks
  const int b = nid >> 4, q0 = (nid & 15) * 64;
  const int t = threadIdx.x, w = t >> 6, lane = t & 63;
  const int lr = lane & 15, lg = lane >> 4;
  const int wqp = w & 1, sh2 = w >> 1;

  __shared__ __align__(16) char lds[34304];
  float* const msk  = (float*)(lds + 32768);
  float* const redm = (float*)(lds + 33280);
  float* const reds = (float*)(lds + 33792);
  char* const PLb = lds;  // P tile (16 KB) overlays buf0 after QK

  if (t < SLN) msk[t] = -10000.0f * (float)mask[b * SLN + t];

  v4f acc[4][2];
#pragma unroll
  for (int fr = 0; fr < 4; ++fr)
#pragma unroll
    for (int j = 0; j < 2; ++j) acc[fr][j] = (v4f){0.f, 0.f, 0.f, 0.f};

  const int rA = (lane >> 3);
  const int cpA = lane & 7;
  const _Float16* gA[4];
#pragma unroll
  for (int g = 0; g < 4; ++g) {
    const int row = w * 32 + g * 8 + rA;
    const int c = cpA ^ (row & 7);
    gA[g] = STf + ((size_t)b * SLN + row) * IDF + c * 8;
  }
  const int dA = w * 4096;  // bytes: 32 rows x 128 B

  const float* gB = input + (size_t)b * IDF * QLN + q0 + wqp * 32 + lr;

  // prologue: A(0) gloads; B(0) load+cvt; A(1) gloads
#pragma unroll
  for (int g = 0; g < 4; ++g) gload16(gA[g], lds + dA + g * 1024);
  v8hf aH[2][2], bH[2][2];
  float tmpB[2][2][8];
#pragma unroll
  for (int kk = 0; kk < 2; ++kk)
#pragma unroll
    for (int j = 0; j < 2; ++j)
#pragma unroll
      for (int e = 0; e < 8; ++e)
        tmpB[kk][j][e] = gB[(size_t)(kk * 32 + lg * 8 + e) * QLN + j * 16];
#pragma unroll
  for (int kk = 0; kk < 2; ++kk)
#pragma unroll
    for (int j = 0; j < 2; ++j)
#pragma unroll
      for (int e = 0; e < 8; ++e) aH[kk][j][e] = (_Float16)tmpB[kk][j][e];
#pragma unroll
  for (int g = 0; g < 4; ++g) gload16(gA[g] + 64, lds + 16384 + dA + g * 1024);

#define QK_WIN(CUROFF, BC, BN, IT, VMC)                                        \
  {                                                                            \
    asm volatile("s_waitcnt vmcnt(" #VMC ")" ::: "memory");                    \
    __builtin_amdgcn_sched_barrier(0);                                         \
    __builtin_amdgcn_s_barrier();                                              \
    __builtin_amdgcn_sched_barrier(0);                                         \
    if ((IT) + 1 < NT2) {                                                      \
      _Pragma("unroll") for (int kk = 0; kk < 2; ++kk)                         \
          _Pragma("unroll") for (int j = 0; j < 2; ++j)                        \
          _Pragma("unroll") for (int e = 0; e < 8; ++e)                        \
          tmpB[kk][j][e] =                                                     \
              gB[(size_t)(((IT) + 1) * 64 + kk * 32 + lg * 8 + e) * QLN +      \
                 j * 16];                                                      \
    }                                                                          \
    __builtin_amdgcn_sched_barrier(0);                                         \
    const char* Ab = lds + (CUROFF);                                           \
    __builtin_amdgcn_s_setprio(1);                                             \
    _Pragma("unroll") for (int fr = 0; fr < 4; ++fr) {                         \
      const int r = sh2 * 64 + fr * 16 + lr;                                   \
      _Pragma("unroll") for (int kk = 0; kk < 2; ++kk) {                       \
        const int cc = (kk * 4 + lg) ^ (r & 7);                                \
        v8hf ah = *(const v8hf*)(Ab + r * 128 + cc * 16);                      \
        _Pragma("unroll") for (int j = 0; j < 2; ++j) {                        \
          acc[fr][j] = MFMAH(ah, BC[kk][j], acc[fr][j], 0, 0, 0);              \
        }                                                                      \
      }                                                                        \
    }                                                                          \
    __builtin_amdgcn_s_setprio(0);                                             \
    __builtin_amdgcn_sched_barrier(0);                                         \
    if ((IT) + 1 < NT2) {                                                      \
      _Pragma("unroll") for (int kk = 0; kk < 2; ++kk)                         \
          _Pragma("unroll") for (int j = 0; j < 2; ++j)                        \
          _Pragma("unroll") for (int e = 0; e < 8; ++e)                        \
          BN[kk][j][e] = (_Float16)tmpB[kk][j][e];                             \
    }                                                                          \
    asm volatile("s_waitcnt lgkmcnt(0)" ::: "memory");                         \
    __builtin_amdgcn_s_barrier();                                              \
    if ((IT) + 2 < NT2) {                                                      \
      _Pragma("unroll") for (int g = 0; g < 4; ++g)                            \
          gload16(gA[g] + (size_t)((IT) + 2) * 64,                             \
                  lds + (CUROFF) + dA + g * 1024);                             \
    }                                                                          \
  }

  for (int it2 = 0; it2 < 5; ++it2) {
    const int itE = it2 * 2;
    QK_WIN(0, aH, bH, itE, 4);
    QK_WIN(16384, bH, aH, itE + 1, 4);
  }
  QK_WIN(0, aH, bH, 10, 4);
  QK_WIN(16384, bH, aH, 11, 0);
#undef QK_WIN

  // softmax over s=128; lane covers q = q0 + (wqp*2+j)*16 + lr, s-half sh2
  float mx[2], sum[2];
#pragma unroll
  for (int j = 0; j < 2; ++j) {
    mx[j] = -3.0e38f;
#pragma unroll
    for (int fr = 0; fr < 4; ++fr)
#pragma unroll
      for (int r = 0; r < 4; ++r) {
        acc[fr][j][r] += msk[sh2 * 64 + fr * 16 + lg * 4 + r];
        mx[j] = fmaxf(mx[j], acc[fr][j][r]);
      }
    mx[j] = fmaxf(mx[j], __shfl_xor(mx[j], 16));
    mx[j] = fmaxf(mx[j], __shfl_xor(mx[j], 32));
    if (lg == 0) redm[sh2 * 64 + wqp * 32 + j * 16 + lr] = mx[j];
  }
  __syncthreads();
#pragma unroll
  for (int j = 0; j < 2; ++j) {
    const int qh = wqp * 32 + j * 16 + lr;
    mx[j] = fmaxf(redm[qh], redm[64 + qh]);
    sum[j] = 0.f;
#pragma unroll
    for (int fr = 0; fr < 4; ++fr)
#pragma unroll
      for (int r = 0; r < 4; ++r) {
        float e = __expf(acc[fr][j][r] - mx[j]);
        acc[fr][j][r] = e;
        sum[j] += e;
      }
    sum[j] += __shfl_xor(sum[j], 16);
    sum[j] += __shfl_xor(sum[j], 32);
    if (lg == 0) reds[sh2 * 64 + wqp * 32 + j * 16 + lr] = sum[j];
  }
  __syncthreads();
#pragma unroll
  for (int j = 0; j < 2; ++j) {
    const int qh = wqp * 32 + j * 16 + lr;
    const float inv = 1.0f / (reds[qh] + reds[64 + qh]);
    const int q = q0 + qh;
#pragma unroll
    for (int fr = 0; fr < 4; ++fr) {
      v4hf hp;
#pragma unroll
      for (int r = 0; r < 4; ++r) {
        float p = acc[fr][j][r] * inv;
        attn_out[((size_t)b * SLN + sh2 * 64 + fr * 16 + lg * 4 + r) * QLN + q] =
            p;
        hp[r] = (_Float16)p;
      }
      const int g = (sh2 * 8 + fr * 2 + (lg >> 1)) ^ lr;
      *(v4hf*)(PLb + qh * 256 + g * 16 + (lg & 1) * 8) = hp;
    }
  }
  __syncthreads();

  // ---- PV: wave -> (qfp = (w&1)*2, islab = (w>>1)*384, 24 i-frags) ----
  const int qfp = (w & 1) * 2;
  const int islab = (w >> 1) * 384;
  v8hf pa0v[4], pa1v[4];
#pragma unroll
  for (int kt = 0; kt < 4; ++kt) {
    const int g0 = (kt * 4 + lg) ^ lr;
    pa0v[kt] = *(const v8hf*)(PLb + (qfp * 16 + lr) * 256 + g0 * 16);
    pa1v[kt] = *(const v8hf*)(PLb + ((qfp + 1) * 16 + lr) * 256 + g0 * 16);
  }
  const _Float16* pShv = Shvf + ((size_t)b * IDF + islab + lr) * SLN + lg * 8;
  float* pWc = wc + ((size_t)b * IDF + islab + lr) * QLN + q0;
#pragma unroll 2
  for (int ifr = 0; ifr < 24; ++ifr) {
    v4f a0 = (v4f){0.f, 0.f, 0.f, 0.f};
    v4f a1 = (v4f){0.f, 0.f, 0.f, 0.f};
#pragma unroll
    for (int kt = 0; kt < 4; ++kt) {
      v8hf bb = *(const v8hf*)(pShv + (size_t)(ifr * 16) * SLN + kt * 32);
      a0 = MFMAH(pa0v[kt], bb, a0, 0, 0, 0);
      a1 = MFMAH(pa1v[kt], bb, a1, 0, 0, 0);
    }
    *(float4*)(pWc + (size_t)(ifr * 16) * QLN + qfp * 16 + lg * 4) =
        make_float4(a0[0], a0[1], a0[2], a0[3]);
    *(float4*)(pWc + (size_t)(ifr * 16) * QLN + (qfp + 1) * 16 + lg * 4) =
        make_float4(a1[0], a1[1], a1[2], a1[3]);
  }
}

// -----------------------------------------------------------------------------
extern "C" void kernel_launch(void* const* d_in, const int* in_sizes, int n_in,
                              void* d_out, int out_size, void* d_ws, size_t ws_size,
                              hipStream_t stream) {
  const float* input   = (const float*)d_in[0];
  const float* context = (const float*)d_in[1];
  const int*   mask    = (const int*)d_in[2];
  const float* w_conv  = (const float*)d_in[3];

  float* out      = (float*)d_out;
  float* wc       = out;
  float* attn_out = out + (size_t)NB * IDF * QLN;

  // ws: STf | Shvf = 12,582,912 B (< 29.36 MB OK).
  // Scratch in wc output region (dead before PV): cTf | Wf.
  const size_t SE = (size_t)NB * SLN * IDF;  // 3,145,728
  _Float16* wsb = (_Float16*)d_ws;
  _Float16* STf  = wsb;
  _Float16* Shvf = STf + SE;
  _Float16* scr  = (_Float16*)wc;
  _Float16* cTf  = scr;
  _Float16* Wf   = cTf + SE;

  prep_k<<<960, 256, 0, stream>>>(w_conv, context, Wf, cTf);
  proj_k<<<dim3(24, NB), 256, 0, stream>>>(cTf, Wf, STf, Shvf);
  qkpv_k<<<512, 256, 0, stream>>>(input, STf, Shvf, mask, wc, attn_out);
}

// Round 25
// 78.074 us; speedup vs baseline: 1.3048x; 1.0160x over previous
//
#include <hip/hip_runtime.h>

#define NB  32
#define IDF 768
#define SLN 128
#define QLN 1024
#define NT2 12    // IDF/64 (BK=64 windows, proj + qkpv)

typedef _Float16 v8hf __attribute__((ext_vector_type(8)));
typedef _Float16 v4hf __attribute__((ext_vector_type(4)));
typedef float    v4f  __attribute__((ext_vector_type(4)));

#define MFMAH __builtin_amdgcn_mfma_f32_16x16x32_f16

__device__ __forceinline__ void gload16(const void* g, void* l) {
  __builtin_amdgcn_global_load_lds(
      (const __attribute__((address_space(1))) void*)g,
      (__attribute__((address_space(3))) void*)l, 16, 0, 0);
}

__device__ __forceinline__ void lbar() {
  asm volatile("s_waitcnt lgkmcnt(0)" ::: "memory");
  __builtin_amdgcn_sched_barrier(0);
  __builtin_amdgcn_s_barrier();
  __builtin_amdgcn_sched_barrier(0);
}

// -----------------------------------------------------------------------------
// K0 prep: blocks 0..575: W f32 -> Wf fp16; blocks 576..959: transpose ctx
// [b][c][s] f32 -> cTf [b][s][c] fp16.  (unchanged, known-good)
// -----------------------------------------------------------------------------
__global__ __launch_bounds__(256) void prep_k(const float* __restrict__ W,
                                              const float* __restrict__ ctx,
                                              _Float16* __restrict__ Wf,
                                              _Float16* __restrict__ cTf) {
  const int bid = blockIdx.x, t = threadIdx.x;
  __shared__ float tl[64][133];
  if (bid < 576) {
    int idx = bid * 1024 + t * 4;
    float4 v = *(const float4*)(W + idx);
    v4hf h;
    h[0] = (_Float16)v.x;
    h[1] = (_Float16)v.y;
    h[2] = (_Float16)v.z;
    h[3] = (_Float16)v.w;
    *(v4hf*)(Wf + idx) = h;
    return;
  }
  const int cid = bid - 576;
  const int b = cid / 12, c0 = (cid % 12) * 64;
#pragma unroll
  for (int j = 0; j < 8; ++j) {
    int u = j * 256 + t;
    int c = u >> 5, s4 = (u & 31) * 4;
    *(float4*)&tl[c][s4] =
        *(const float4*)(ctx + ((size_t)b * IDF + c0 + c) * SLN + s4);
  }
  __syncthreads();
#pragma unroll
  for (int j = 0; j < 8; ++j) {
    int u = j * 256 + t;
    int s = u >> 4, c4 = (u & 15) * 4;
    v4hf h;
#pragma unroll
    for (int e = 0; e < 4; ++e) h[e] = (_Float16)tl[c4 + e][s];
    *(v4hf*)(cTf + ((size_t)b * SLN + s) * IDF + c0 + c4) = h;
  }
}

// -----------------------------------------------------------------------------
// K1 proj: round-24 exact (BK=64, padded LDS [128][72], known-good).
// -----------------------------------------------------------------------------
__global__ __launch_bounds__(256) void proj_k(const _Float16* __restrict__ cTf,
                                              const _Float16* __restrict__ Wf,
                                              _Float16* __restrict__ STf,
                                              _Float16* __restrict__ Shvf) {
  const int b = blockIdx.y, o0 = blockIdx.x * 32;
  const int t = threadIdx.x, w = t >> 6, lane = t & 63;
  const int lr = lane & 15, lg = lane >> 4;
  const int ws = w >> 1, wq = w & 1;
  __shared__ _Float16 AL[128][72];

  v4f acc[4];
#pragma unroll
  for (int fr = 0; fr < 4; ++fr) acc[fr] = (v4f){0.f, 0.f, 0.f, 0.f};

  const int ra = t >> 1;
  const int cb = (t & 1) * 4;
  const _Float16* pA = cTf + ((size_t)b * SLN + ra) * IDF + cb * 8;
  const size_t wOff = (size_t)(o0 + wq * 16 + lr) * IDF + lg * 8;

  uint4 aS0, aS1, aS2, aS3, bS0, bS1, bS2, bS3;
  v8hf wc0, wc1, wn0, wn1;
  aS0 = *(const uint4*)(pA);
  aS1 = *(const uint4*)(pA + 8);
  aS2 = *(const uint4*)(pA + 16);
  aS3 = *(const uint4*)(pA + 24);
  bS0 = *(const uint4*)(pA + 64);
  bS1 = *(const uint4*)(pA + 72);
  bS2 = *(const uint4*)(pA + 80);
  bS3 = *(const uint4*)(pA + 88);
  wc0 = *(const v8hf*)(Wf + wOff);
  wc1 = *(const v8hf*)(Wf + wOff + 32);

#define PROJ_BODY(S0, S1, S2, S3, IT)                                          \
  {                                                                            \
    lbar();                                                                    \
    *(uint4*)&AL[ra][(cb + 0) * 8] = S0;                                       \
    *(uint4*)&AL[ra][(cb + 1) * 8] = S1;                                       \
    *(uint4*)&AL[ra][(cb + 2) * 8] = S2;                                       \
    *(uint4*)&AL[ra][(cb + 3) * 8] = S3;                                       \
    if ((IT) + 2 < NT2) {                                                      \
      S0 = *(const uint4*)(pA + ((IT) + 2) * 64);                              \
      S1 = *(const uint4*)(pA + ((IT) + 2) * 64 + 8);                          \
      S2 = *(const uint4*)(pA + ((IT) + 2) * 64 + 16);                         \
      S3 = *(const uint4*)(pA + ((IT) + 2) * 64 + 24);                         \
    }                                                                          \
    if ((IT) + 1 < NT2) {                                                      \
      wn0 = *(const v8hf*)(Wf + wOff + ((IT) + 1) * 64);                       \
      wn1 = *(const v8hf*)(Wf + wOff + ((IT) + 1) * 64 + 32);                  \
    }                                                                          \
    lbar();                                                                    \
    _Pragma("unroll") for (int fr = 0; fr < 4; ++fr) {                         \
      const int r = ws * 64 + fr * 16 + lr;                                    \
      v8hf ah0 = *(const v8hf*)&AL[r][lg * 8];                                 \
      acc[fr] = MFMAH(ah0, wc0, acc[fr], 0, 0, 0);                             \
      v8hf ah1 = *(const v8hf*)&AL[r][32 + lg * 8];                            \
      acc[fr] = MFMAH(ah1, wc1, acc[fr], 0, 0, 0);                             \
    }                                                                          \
    wc0 = wn0;                                                                 \
    wc1 = wn1;                                                                 \
  }

  for (int it2 = 0; it2 < NT2 / 2; ++it2) {
    const int itE = it2 * 2;
    PROJ_BODY(aS0, aS1, aS2, aS3, itE);
    PROJ_BODY(bS0, bS1, bS2, bS3, itE + 1);
  }
#undef PROJ_BODY

  const int o = o0 + wq * 16 + lr;
#pragma unroll
  for (int fr = 0; fr < 4; ++fr) {
    v4hf hp;
#pragma unroll
    for (int r = 0; r < 4; ++r) {
      int s = ws * 64 + fr * 16 + lg * 4 + r;
      _Float16 h = (_Float16)acc[fr][r];
      STf[((size_t)b * SLN + s) * IDF + o] = h;
      hp[r] = h;
    }
    *(v4hf*)(Shvf + ((size_t)b * IDF + o) * SLN + ws * 64 + fr * 16 + lg * 4) =
        hp;
  }
}

// -----------------------------------------------------------------------------
// K2 qkpv: wave-per-q-frag remap. 256 thr, 4 waves; wave w owns q-frag
// q = q0 + w*16 + lr with FULL s (acc[8]). B loads 16/wave/window (halved,
// dedup'd); softmax pure-shfl (lanes lr,lr+16,lr+32,lr+48 partition s=128),
// no LDS reduce, no extra barriers. A staging unchanged (4 gloads/wave/win,
// chunk-XOR c' = c ^ (r&7) presourced). MFMA 16/wave/window, k-ascending ->
// logits bit-identical to round 24. vmcnt entry 4, final 0. LDS 33.3 KB.
// -----------------------------------------------------------------------------
__global__ __launch_bounds__(256, 4) void qkpv_k(const float* __restrict__ input,
                                                 const _Float16* __restrict__ STf,
                                                 const _Float16* __restrict__ Shvf,
                                                 const int* __restrict__ mask,
                                                 float* __restrict__ wc,
                                                 float* __restrict__ attn_out) {
  const int bid = blockIdx.x;
  const int nid = (bid & 7) * 64 + (bid >> 3);  // XCD swizzle, 512 blocks
  const int b = nid >> 4, q0 = (nid & 15) * 64;
  const int t = threadIdx.x, w = t >> 6, lane = t & 63;
  const int lr = lane & 15, lg = lane >> 4;

  // LDS: buf0 @0 (16K [128 r][64 k] fp16 swizzled), buf1 @16384,
  // msk @32768 (512B). Total 33280 B. PL (16 KB) overlays buf0 after QK.
  __shared__ __align__(16) char lds[33280];
  float* const msk = (float*)(lds + 32768);
  char* const PLb = lds;

  if (t < SLN) msk[t] = -10000.0f * (float)mask[b * SLN + t];

  v4f acc[8];
#pragma unroll
  for (int fr = 0; fr < 8; ++fr) acc[fr] = (v4f){0.f, 0.f, 0.f, 0.f};

  // A staging: wave w stages rows [w*32, w*32+32) x 64 k as 4 gloads.
  const int rA = (lane >> 3);
  const int cpA = lane & 7;
  const _Float16* gA[4];
#pragma unroll
  for (int g = 0; g < 4; ++g) {
    const int row = w * 32 + g * 8 + rA;
    const int c = cpA ^ (row & 7);
    gA[g] = STf + ((size_t)b * SLN + row) * IDF + c * 8;
  }
  const int dA = w * 4096;  // bytes: 32 rows x 128 B

  // B direct-global: wave w covers q = q0 + w*16 + lr; k-steps kk=0,1
  const float* gB = input + (size_t)b * IDF * QLN + q0 + w * 16 + lr;

  // prologue: A(0) gloads; B(0) load+cvt; A(1) gloads
#pragma unroll
  for (int g = 0; g < 4; ++g) gload16(gA[g], lds + dA + g * 1024);
  v8hf aH[2], bH[2];
  float tmpB[2][8];
#pragma unroll
  for (int kk = 0; kk < 2; ++kk)
#pragma unroll
    for (int e = 0; e < 8; ++e)
      tmpB[kk][e] = gB[(size_t)(kk * 32 + lg * 8 + e) * QLN];
#pragma unroll
  for (int kk = 0; kk < 2; ++kk)
#pragma unroll
    for (int e = 0; e < 8; ++e) aH[kk][e] = (_Float16)tmpB[kk][e];
#pragma unroll
  for (int g = 0; g < 4; ++g) gload16(gA[g] + 64, lds + 16384 + dA + g * 1024);

#define QK_WIN(CUROFF, BC, BN, IT, VMC)                                        \
  {                                                                            \
    asm volatile("s_waitcnt vmcnt(" #VMC ")" ::: "memory");                    \
    __builtin_amdgcn_sched_barrier(0);                                         \
    __builtin_amdgcn_s_barrier();                                              \
    __builtin_amdgcn_sched_barrier(0);                                         \
    if ((IT) + 1 < NT2) {                                                      \
      _Pragma("unroll") for (int kk = 0; kk < 2; ++kk)                         \
          _Pragma("unroll") for (int e = 0; e < 8; ++e)                        \
          tmpB[kk][e] =                                                        \
              gB[(size_t)(((IT) + 1) * 64 + kk * 32 + lg * 8 + e) * QLN];      \
    }                                                                          \
    __builtin_amdgcn_sched_barrier(0);                                         \
    const char* Ab = lds + (CUROFF);                                           \
    __builtin_amdgcn_s_setprio(1);                                             \
    _Pragma("unroll") for (int fr = 0; fr < 8; ++fr) {                         \
      const int r = fr * 16 + lr;                                              \
      _Pragma("unroll") for (int kk = 0; kk < 2; ++kk) {                       \
        const int cc = (kk * 4 + lg) ^ (r & 7);                                \
        v8hf ah = *(const v8hf*)(Ab + r * 128 + cc * 16);                      \
        acc[fr] = MFMAH(ah, BC[kk], acc[fr], 0, 0, 0);                         \
      }                                                                        \
    }                                                                          \
    __builtin_amdgcn_s_setprio(0);                                             \
    __builtin_amdgcn_sched_barrier(0);                                         \
    if ((IT) + 1 < NT2) {                                                      \
      _Pragma("unroll") for (int kk = 0; kk < 2; ++kk)                         \
          _Pragma("unroll") for (int e = 0; e < 8; ++e)                        \
          BN[kk][e] = (_Float16)tmpB[kk][e];                                   \
    }                                                                          \
    asm volatile("s_waitcnt lgkmcnt(0)" ::: "memory");                         \
    __builtin_amdgcn_s_barrier();                                              \
    if ((IT) + 2 < NT2) {                                                      \
      _Pragma("unroll") for (int g = 0; g < 4; ++g)                            \
          gload16(gA[g] + (size_t)((IT) + 2) * 64,                             \
                  lds + (CUROFF) + dA + g * 1024);                             \
    }                                                                          \
  }

  for (int it2 = 0; it2 < 5; ++it2) {
    const int itE = it2 * 2;
    QK_WIN(0, aH, bH, itE, 4);
    QK_WIN(16384, bH, aH, itE + 1, 4);
  }
  QK_WIN(0, aH, bH, 10, 4);
  QK_WIN(16384, bH, aH, 11, 0);
#undef QK_WIN

  // softmax over s=128 for q = q0 + w*16 + lr; pure shfl (lanes lr, lr+16,
  // lr+32, lr+48 partition s). No LDS, no barriers.
  const int qh = w * 16 + lr;
  float mx = -3.0e38f;
#pragma unroll
  for (int fr = 0; fr < 8; ++fr)
#pragma unroll
    for (int r = 0; r < 4; ++r) {
      acc[fr][r] += msk[fr * 16 + lg * 4 + r];
      mx = fmaxf(mx, acc[fr][r]);
    }
  mx = fmaxf(mx, __shfl_xor(mx, 16));
  mx = fmaxf(mx, __shfl_xor(mx, 32));
  float sum = 0.f;
#pragma unroll
  for (int fr = 0; fr < 8; ++fr)
#pragma unroll
    for (int r = 0; r < 4; ++r) {
      float e = __expf(acc[fr][r] - mx);
      acc[fr][r] = e;
      sum += e;
    }
  sum += __shfl_xor(sum, 16);
  sum += __shfl_xor(sum, 32);
  const float inv = 1.0f / sum;
  const int q = q0 + qh;
#pragma unroll
  for (int fr = 0; fr < 8; ++fr) {
    v4hf hp;
#pragma unroll
    for (int r = 0; r < 4; ++r) {
      float p = acc[fr][r] * inv;
      attn_out[((size_t)b * SLN + fr * 16 + lg * 4 + r) * QLN + q] = p;
      hp[r] = (_Float16)p;
    }
    // PL swizzled write (overlays buf0): s-group = fr*2 + (lg>>1)
    const int g = (fr * 2 + (lg >> 1)) ^ lr;
    *(v4hf*)(PLb + qh * 256 + g * 16 + (lg & 1) * 8) = hp;
  }
  __syncthreads();

  // ---- PV: wave -> (qfp = (w&1)*2, islab = (w>>1)*384, 24 i-frags) ----
  const int qfp = (w & 1) * 2;
  const int islab = (w >> 1) * 384;
  v8hf pa0v[4], pa1v[4];
#pragma unroll
  for (int kt = 0; kt < 4; ++kt) {
    const int g0 = (kt * 4 + lg) ^ lr;
    pa0v[kt] = *(const v8hf*)(PLb + (qfp * 16 + lr) * 256 + g0 * 16);
    pa1v[kt] = *(const v8hf*)(PLb + ((qfp + 1) * 16 + lr) * 256 + g0 * 16);
  }
  const _Float16* pShv = Shvf + ((size_t)b * IDF + islab + lr) * SLN + lg * 8;
  float* pWc = wc + ((size_t)b * IDF + islab + lr) * QLN + q0;
#pragma unroll 2
  for (int ifr = 0; ifr < 24; ++ifr) {
    v4f a0 = (v4f){0.f, 0.f, 0.f, 0.f};
    v4f a1 = (v4f){0.f, 0.f, 0.f, 0.f};
#pragma unroll
    for (int kt = 0; kt < 4; ++kt) {
      v8hf bb = *(const v8hf*)(pShv + (size_t)(ifr * 16) * SLN + kt * 32);
      a0 = MFMAH(pa0v[kt], bb, a0, 0, 0, 0);
      a1 = MFMAH(pa1v[kt], bb, a1, 0, 0, 0);
    }
    *(float4*)(pWc + (size_t)(ifr * 16) * QLN + qfp * 16 + lg * 4) =
        make_float4(a0[0], a0[1], a0[2], a0[3]);
    *(float4*)(pWc + (size_t)(ifr * 16) * QLN + (qfp + 1) * 16 + lg * 4) =
        make_float4(a1[0], a1[1], a1[2], a1[3]);
  }
}

// -----------------------------------------------------------------------------
extern "C" void kernel_launch(void* const* d_in, const int* in_sizes, int n_in,
                              void* d_out, int out_size, void* d_ws, size_t ws_size,
                              hipStream_t stream) {
  const float* input   = (const float*)d_in[0];
  const float* context = (const float*)d_in[1];
  const int*   mask    = (const int*)d_in[2];
  const float* w_conv  = (const float*)d_in[3];

  float* out      = (float*)d_out;
  float* wc       = out;
  float* attn_out = out + (size_t)NB * IDF * QLN;

  // ws: STf | Shvf = 12,582,912 B (< 29.36 MB OK).
  // Scratch in wc output region (dead before PV): cTf | Wf.
  const size_t SE = (size_t)NB * SLN * IDF;  // 3,145,728
  _Float16* wsb = (_Float16*)d_ws;
  _Float16* STf  = wsb;
  _Float16* Shvf = STf + SE;
  _Float16* scr  = (_Float16*)wc;
  _Float16* cTf  = scr;
  _Float16* Wf   = cTf + SE;

  prep_k<<<960, 256, 0, stream>>>(w_conv, context, Wf, cTf);
  proj_k<<<dim3(24, NB), 256, 0, stream>>>(cTf, Wf, STf, Shvf);
  qkpv_k<<<512, 256, 0, stream>>>(input, STf, Shvf, mask, wc, attn_out);
}

// Round 26
// 74.458 us; speedup vs baseline: 1.3681x; 1.0486x over previous
//
#include <hip/hip_runtime.h>

#define NB  32
#define IDF 768
#define SLN 128
#define QLN 1024
#define NT2 12    // IDF/64 (BK=64 windows, proj + qkpv)

typedef _Float16 v8hf __attribute__((ext_vector_type(8)));
typedef _Float16 v4hf __attribute__((ext_vector_type(4)));
typedef float    v4f  __attribute__((ext_vector_type(4)));

#define MFMAH __builtin_amdgcn_mfma_f32_16x16x32_f16

__device__ __forceinline__ void gload16(const void* g, void* l) {
  __builtin_amdgcn_global_load_lds(
      (const __attribute__((address_space(1))) void*)g,
      (__attribute__((address_space(3))) void*)l, 16, 0, 0);
}

__device__ __forceinline__ void lbar() {
  asm volatile("s_waitcnt lgkmcnt(0)" ::: "memory");
  __builtin_amdgcn_sched_barrier(0);
  __builtin_amdgcn_s_barrier();
  __builtin_amdgcn_sched_barrier(0);
}

// -----------------------------------------------------------------------------
// K0 prep: blocks 0..575: W f32 -> Wf fp16; blocks 576..959: transpose ctx
// [b][c][s] f32 -> cTf [b][s][c] fp16.  (unchanged, known-good)
// -----------------------------------------------------------------------------
__global__ __launch_bounds__(256) void prep_k(const float* __restrict__ W,
                                              const float* __restrict__ ctx,
                                              _Float16* __restrict__ Wf,
                                              _Float16* __restrict__ cTf) {
  const int bid = blockIdx.x, t = threadIdx.x;
  __shared__ float tl[64][133];
  if (bid < 576) {
    int idx = bid * 1024 + t * 4;
    float4 v = *(const float4*)(W + idx);
    v4hf h;
    h[0] = (_Float16)v.x;
    h[1] = (_Float16)v.y;
    h[2] = (_Float16)v.z;
    h[3] = (_Float16)v.w;
    *(v4hf*)(Wf + idx) = h;
    return;
  }
  const int cid = bid - 576;
  const int b = cid / 12, c0 = (cid % 12) * 64;
#pragma unroll
  for (int j = 0; j < 8; ++j) {
    int u = j * 256 + t;
    int c = u >> 5, s4 = (u & 31) * 4;
    *(float4*)&tl[c][s4] =
        *(const float4*)(ctx + ((size_t)b * IDF + c0 + c) * SLN + s4);
  }
  __syncthreads();
#pragma unroll
  for (int j = 0; j < 8; ++j) {
    int u = j * 256 + t;
    int s = u >> 4, c4 = (u & 15) * 4;
    v4hf h;
#pragma unroll
    for (int e = 0; e < 4; ++e) h[e] = (_Float16)tl[c4 + e][s];
    *(v4hf*)(cTf + ((size_t)b * SLN + s) * IDF + c0 + c4) = h;
  }
}

// -----------------------------------------------------------------------------
// K1 proj: round-24 exact (BK=64, padded LDS [128][72], known-good).
// -----------------------------------------------------------------------------
__global__ __launch_bounds__(256) void proj_k(const _Float16* __restrict__ cTf,
                                              const _Float16* __restrict__ Wf,
                                              _Float16* __restrict__ STf,
                                              _Float16* __restrict__ Shvf) {
  const int b = blockIdx.y, o0 = blockIdx.x * 32;
  const int t = threadIdx.x, w = t >> 6, lane = t & 63;
  const int lr = lane & 15, lg = lane >> 4;
  const int ws = w >> 1, wq = w & 1;
  __shared__ _Float16 AL[128][72];

  v4f acc[4];
#pragma unroll
  for (int fr = 0; fr < 4; ++fr) acc[fr] = (v4f){0.f, 0.f, 0.f, 0.f};

  const int ra = t >> 1;
  const int cb = (t & 1) * 4;
  const _Float16* pA = cTf + ((size_t)b * SLN + ra) * IDF + cb * 8;
  const size_t wOff = (size_t)(o0 + wq * 16 + lr) * IDF + lg * 8;

  uint4 aS0, aS1, aS2, aS3, bS0, bS1, bS2, bS3;
  v8hf wc0, wc1, wn0, wn1;
  aS0 = *(const uint4*)(pA);
  aS1 = *(const uint4*)(pA + 8);
  aS2 = *(const uint4*)(pA + 16);
  aS3 = *(const uint4*)(pA + 24);
  bS0 = *(const uint4*)(pA + 64);
  bS1 = *(const uint4*)(pA + 72);
  bS2 = *(const uint4*)(pA + 80);
  bS3 = *(const uint4*)(pA + 88);
  wc0 = *(const v8hf*)(Wf + wOff);
  wc1 = *(const v8hf*)(Wf + wOff + 32);

#define PROJ_BODY(S0, S1, S2, S3, IT)                                          \
  {                                                                            \
    lbar();                                                                    \
    *(uint4*)&AL[ra][(cb + 0) * 8] = S0;                                       \
    *(uint4*)&AL[ra][(cb + 1) * 8] = S1;                                       \
    *(uint4*)&AL[ra][(cb + 2) * 8] = S2;                                       \
    *(uint4*)&AL[ra][(cb + 3) * 8] = S3;                                       \
    if ((IT) + 2 < NT2) {                                                      \
      S0 = *(const uint4*)(pA + ((IT) + 2) * 64);                              \
      S1 = *(const uint4*)(pA + ((IT) + 2) * 64 + 8);                          \
      S2 = *(const uint4*)(pA + ((IT) + 2) * 64 + 16);                         \
      S3 = *(const uint4*)(pA + ((IT) + 2) * 64 + 24);                         \
    }                                                                          \
    if ((IT) + 1 < NT2) {                                                      \
      wn0 = *(const v8hf*)(Wf + wOff + ((IT) + 1) * 64);                       \
      wn1 = *(const v8hf*)(Wf + wOff + ((IT) + 1) * 64 + 32);                  \
    }                                                                          \
    lbar();                                                                    \
    _Pragma("unroll") for (int fr = 0; fr < 4; ++fr) {                         \
      const int r = ws * 64 + fr * 16 + lr;                                    \
      v8hf ah0 = *(const v8hf*)&AL[r][lg * 8];                                 \
      acc[fr] = MFMAH(ah0, wc0, acc[fr], 0, 0, 0);                             \
      v8hf ah1 = *(const v8hf*)&AL[r][32 + lg * 8];                            \
      acc[fr] = MFMAH(ah1, wc1, acc[fr], 0, 0, 0);                             \
    }                                                                          \
    wc0 = wn0;                                                                 \
    wc1 = wn1;                                                                 \
  }

  for (int it2 = 0; it2 < NT2 / 2; ++it2) {
    const int itE = it2 * 2;
    PROJ_BODY(aS0, aS1, aS2, aS3, itE);
    PROJ_BODY(bS0, bS1, bS2, bS3, itE + 1);
  }
#undef PROJ_BODY

  const int o = o0 + wq * 16 + lr;
#pragma unroll
  for (int fr = 0; fr < 4; ++fr) {
    v4hf hp;
#pragma unroll
    for (int r = 0; r < 4; ++r) {
      int s = ws * 64 + fr * 16 + lg * 4 + r;
      _Float16 h = (_Float16)acc[fr][r];
      STf[((size_t)b * SLN + s) * IDF + o] = h;
      hp[r] = h;
    }
    *(v4hf*)(Shvf + ((size_t)b * IDF + o) * SLN + ws * 64 + fr * 16 + lg * 4) =
        hp;
  }
}

// -----------------------------------------------------------------------------
// K2 qkpv: B staged via gload_lds too -> NO forced vmcnt(0) drain per window.
// Per wave per window: 4 A-gloads + 4 B-gloads; entry vmcnt(8) steady (next
// window's 8 stay in flight), final 0. B tile [64k][64q] f32 16KB/buf, linear
// dest, 16B-chunk XOR presource (c_glob = c ^ (row&15)); read chunk =
// (q>>2) ^ (row&15), word q&3 (<=2-way banks). cvt f32->fp16 after LDS read
// (same values/order as round 25 -> bit-identical). Wave = one q-frag, full
// s (acc[8]); pure-shfl softmax; PV unchanged. LDS 64.5 KB; VGPR ~60.
// -----------------------------------------------------------------------------
__global__ __launch_bounds__(256, 2) void qkpv_k(const float* __restrict__ input,
                                                 const _Float16* __restrict__ STf,
                                                 const _Float16* __restrict__ Shvf,
                                                 const int* __restrict__ mask,
                                                 float* __restrict__ wc,
                                                 float* __restrict__ attn_out) {
  const int bid = blockIdx.x;
  const int nid = (bid & 7) * 64 + (bid >> 3);  // XCD swizzle, 512 blocks
  const int b = nid >> 4, q0 = (nid & 15) * 64;
  const int t = threadIdx.x, w = t >> 6, lane = t & 63;
  const int lr = lane & 15, lg = lane >> 4;

  // LDS: bufA0 @0 (16K), bufB0 @16384 (16K), bufA1 @32768, bufB1 @49152,
  // msk @65536 (512B). Total 66048 B. PL (16 KB) overlays bufA0 after QK.
  __shared__ __align__(16) char lds[66048];
  float* const msk = (float*)(lds + 65536);
  char* const PLb = lds;

  if (t < SLN) msk[t] = -10000.0f * (float)mask[b * SLN + t];

  v4f acc[8];
#pragma unroll
  for (int fr = 0; fr < 8; ++fr) acc[fr] = (v4f){0.f, 0.f, 0.f, 0.f};

  // A staging (unchanged): wave w stages ST rows [w*32,+32) x 64 k, 4 gloads,
  // chunk-XOR presource c' = c ^ (row&7).
  const int rAl = (lane >> 3);
  const int cpA = lane & 7;
  const _Float16* gA[4];
#pragma unroll
  for (int g = 0; g < 4; ++g) {
    const int row = w * 32 + g * 8 + rAl;
    const int c = cpA ^ (row & 7);
    gA[g] = STf + ((size_t)b * SLN + row) * IDF + c * 8;
  }
  const int dA = w * 4096;  // within A buffer

  // B staging: wave w stages input rows (k) [w*16,+16) x 64 q f32, 4 gloads.
  // lane l -> row w*16 + g*4 + (l>>4), chunk l&15; global q-group
  // 4*((l&15) ^ (row&15)).
  const float* gBp[4];
#pragma unroll
  for (int g = 0; g < 4; ++g) {
    const int row = w * 16 + g * 4 + (lane >> 4);
    gBp[g] = input + ((size_t)b * IDF + row) * QLN + q0 +
             4 * ((lane & 15) ^ (row & 15));
  }
  const int dB = w * 4096;  // within B buffer

  // prologue: t=0 (A x4, B x4), t=1 (A x4, B x4)  [per-wave FIFO order]
#pragma unroll
  for (int g = 0; g < 4; ++g) gload16(gA[g], lds + dA + g * 1024);
#pragma unroll
  for (int g = 0; g < 4; ++g) gload16(gBp[g], lds + 16384 + dB + g * 1024);
#pragma unroll
  for (int g = 0; g < 4; ++g) gload16(gA[g] + 64, lds + 32768 + dA + g * 1024);
#pragma unroll
  for (int g = 0; g < 4; ++g)
    gload16(gBp[g] + (size_t)64 * QLN, lds + 49152 + dB + g * 1024);

  const int qc = w * 4 + (lr >> 2);  // q>>2 within tile
  const int qw = lr & 3;             // q word within chunk

#define QK_WIN(AOFF, BOFF, IT, VMC)                                            \
  {                                                                            \
    asm volatile("s_waitcnt vmcnt(" #VMC ")" ::: "memory");                    \
    __builtin_amdgcn_sched_barrier(0);                                         \
    __builtin_amdgcn_s_barrier();                                              \
    __builtin_amdgcn_sched_barrier(0);                                         \
    const char* Ab = lds + (AOFF);                                             \
    const char* Bb = lds + (BOFF);                                             \
    v8hf bh[2];                                                                \
    _Pragma("unroll") for (int kk = 0; kk < 2; ++kk)                           \
        _Pragma("unroll") for (int e = 0; e < 8; ++e) {                        \
      const int row = kk * 32 + lg * 8 + e;                                    \
      const int ch = qc ^ (row & 15);                                          \
      float v = *(const float*)(Bb + row * 256 + ch * 16 + qw * 4);            \
      bh[kk][e] = (_Float16)v;                                                 \
    }                                                                          \
    __builtin_amdgcn_s_setprio(1);                                             \
    _Pragma("unroll") for (int fr = 0; fr < 8; ++fr) {                         \
      const int r = fr * 16 + lr;                                              \
      _Pragma("unroll") for (int kk = 0; kk < 2; ++kk) {                       \
        const int cc = (kk * 4 + lg) ^ (r & 7);                                \
        v8hf ah = *(const v8hf*)(Ab + r * 128 + cc * 16);                      \
        acc[fr] = MFMAH(ah, bh[kk], acc[fr], 0, 0, 0);                         \
      }                                                                        \
    }                                                                          \
    __builtin_amdgcn_s_setprio(0);                                             \
    asm volatile("s_waitcnt lgkmcnt(0)" ::: "memory");                         \
    __builtin_amdgcn_s_barrier();                                              \
    if ((IT) + 2 < NT2) {                                                      \
      _Pragma("unroll") for (int g = 0; g < 4; ++g)                            \
          gload16(gA[g] + (size_t)((IT) + 2) * 64,                             \
                  lds + (AOFF) + dA + g * 1024);                               \
      _Pragma("unroll") for (int g = 0; g < 4; ++g)                            \
          gload16(gBp[g] + (size_t)((IT) + 2) * 64 * QLN,                      \
                  lds + (BOFF) + dB + g * 1024);                               \
    }                                                                          \
  }

  for (int it2 = 0; it2 < 5; ++it2) {
    const int itE = it2 * 2;
    QK_WIN(0, 16384, itE, 8);
    QK_WIN(32768, 49152, itE + 1, 8);
  }
  QK_WIN(0, 16384, 10, 8);
  QK_WIN(32768, 49152, 11, 0);
#undef QK_WIN

  // softmax over s=128 for q = q0 + w*16 + lr; pure shfl (lanes lr, lr+16,
  // lr+32, lr+48 partition s). No LDS reduce, no barriers.
  const int qh = w * 16 + lr;
  float mx = -3.0e38f;
#pragma unroll
  for (int fr = 0; fr < 8; ++fr)
#pragma unroll
    for (int r = 0; r < 4; ++r) {
      acc[fr][r] += msk[fr * 16 + lg * 4 + r];
      mx = fmaxf(mx, acc[fr][r]);
    }
  mx = fmaxf(mx, __shfl_xor(mx, 16));
  mx = fmaxf(mx, __shfl_xor(mx, 32));
  float sum = 0.f;
#pragma unroll
  for (int fr = 0; fr < 8; ++fr)
#pragma unroll
    for (int r = 0; r < 4; ++r) {
      float e = __expf(acc[fr][r] - mx);
      acc[fr][r] = e;
      sum += e;
    }
  sum += __shfl_xor(sum, 16);
  sum += __shfl_xor(sum, 32);
  const float inv = 1.0f / sum;
  const int q = q0 + qh;
#pragma unroll
  for (int fr = 0; fr < 8; ++fr) {
    v4hf hp;
#pragma unroll
    for (int r = 0; r < 4; ++r) {
      float p = acc[fr][r] * inv;
      attn_out[((size_t)b * SLN + fr * 16 + lg * 4 + r) * QLN + q] = p;
      hp[r] = (_Float16)p;
    }
    // PL swizzled write (overlays bufA0): s-group = fr*2 + (lg>>1)
    const int g = (fr * 2 + (lg >> 1)) ^ lr;
    *(v4hf*)(PLb + qh * 256 + g * 16 + (lg & 1) * 8) = hp;
  }
  __syncthreads();

  // ---- PV: wave -> (qfp = (w&1)*2, islab = (w>>1)*384, 24 i-frags) ----
  const int qfp = (w & 1) * 2;
  const int islab = (w >> 1) * 384;
  v8hf pa0v[4], pa1v[4];
#pragma unroll
  for (int kt = 0; kt < 4; ++kt) {
    const int g0 = (kt * 4 + lg) ^ lr;
    pa0v[kt] = *(const v8hf*)(PLb + (qfp * 16 + lr) * 256 + g0 * 16);
    pa1v[kt] = *(const v8hf*)(PLb + ((qfp + 1) * 16 + lr) * 256 + g0 * 16);
  }
  const _Float16* pShv = Shvf + ((size_t)b * IDF + islab + lr) * SLN + lg * 8;
  float* pWc = wc + ((size_t)b * IDF + islab + lr) * QLN + q0;
#pragma unroll 2
  for (int ifr = 0; ifr < 24; ++ifr) {
    v4f a0 = (v4f){0.f, 0.f, 0.f, 0.f};
    v4f a1 = (v4f){0.f, 0.f, 0.f, 0.f};
#pragma unroll
    for (int kt = 0; kt < 4; ++kt) {
      v8hf bb = *(const v8hf*)(pShv + (size_t)(ifr * 16) * SLN + kt * 32);
      a0 = MFMAH(pa0v[kt], bb, a0, 0, 0, 0);
      a1 = MFMAH(pa1v[kt], bb, a1, 0, 0, 0);
    }
    *(float4*)(pWc + (size_t)(ifr * 16) * QLN + qfp * 16 + lg * 4) =
        make_float4(a0[0], a0[1], a0[2], a0[3]);
    *(float4*)(pWc + (size_t)(ifr * 16) * QLN + (qfp + 1) * 16 + lg * 4) =
        make_float4(a1[0], a1[1], a1[2], a1[3]);
  }
}

// -----------------------------------------------------------------------------
extern "C" void kernel_launch(void* const* d_in, const int* in_sizes, int n_in,
                              void* d_out, int out_size, void* d_ws, size_t ws_size,
                              hipStream_t stream) {
  const float* input   = (const float*)d_in[0];
  const float* context = (const float*)d_in[1];
  const int*   mask    = (const int*)d_in[2];
  const float* w_conv  = (const float*)d_in[3];

  float* out      = (float*)d_out;
  float* wc       = out;
  float* attn_out = out + (size_t)NB * IDF * QLN;

  // ws: STf | Shvf = 12,582,912 B (< 29.36 MB OK).
  // Scratch in wc output region (dead before PV): cTf | Wf.
  const size_t SE = (size_t)NB * SLN * IDF;  // 3,145,728
  _Float16* wsb = (_Float16*)d_ws;
  _Float16* STf  = wsb;
  _Float16* Shvf = STf + SE;
  _Float16* scr  = (_Float16*)wc;
  _Float16* cTf  = scr;
  _Float16* Wf   = cTf + SE;

  prep_k<<<960, 256, 0, stream>>>(w_conv, context, Wf, cTf);
  proj_k<<<dim3(24, NB), 256, 0, stream>>>(cTf, Wf, STf, Shvf);
  qkpv_k<<<512, 256, 0, stream>>>(input, STf, Shvf, mask, wc, attn_out);
}

// Round 27
// 74.024 us; speedup vs baseline: 1.3762x; 1.0059x over previous
//
#include <hip/hip_runtime.h>

#define NB  32
#define IDF 768
#define SLN 128
#define QLN 1024
#define NT2 12    // IDF/64 (BK=64 windows, proj + qkpv)

typedef _Float16 v8hf __attribute__((ext_vector_type(8)));
typedef _Float16 v4hf __attribute__((ext_vector_type(4)));
typedef float    v4f  __attribute__((ext_vector_type(4)));

#define MFMAH __builtin_amdgcn_mfma_f32_16x16x32_f16

__device__ __forceinline__ void gload16(const void* g, void* l) {
  __builtin_amdgcn_global_load_lds(
      (const __attribute__((address_space(1))) void*)g,
      (__attribute__((address_space(3))) void*)l, 16, 0, 0);
}

__device__ __forceinline__ void lbar() {
  asm volatile("s_waitcnt lgkmcnt(0)" ::: "memory");
  __builtin_amdgcn_sched_barrier(0);
  __builtin_amdgcn_s_barrier();
  __builtin_amdgcn_sched_barrier(0);
}

// -----------------------------------------------------------------------------
// K0 prep: blocks 0..575: W f32 -> Wf fp16; blocks 576..959: transpose ctx
// [b][c][s] f32 -> cTf [b][s][c] fp16.  (unchanged, known-good)
// -----------------------------------------------------------------------------
__global__ __launch_bounds__(256) void prep_k(const float* __restrict__ W,
                                              const float* __restrict__ ctx,
                                              _Float16* __restrict__ Wf,
                                              _Float16* __restrict__ cTf) {
  const int bid = blockIdx.x, t = threadIdx.x;
  __shared__ float tl[64][133];
  if (bid < 576) {
    int idx = bid * 1024 + t * 4;
    float4 v = *(const float4*)(W + idx);
    v4hf h;
    h[0] = (_Float16)v.x;
    h[1] = (_Float16)v.y;
    h[2] = (_Float16)v.z;
    h[3] = (_Float16)v.w;
    *(v4hf*)(Wf + idx) = h;
    return;
  }
  const int cid = bid - 576;
  const int b = cid / 12, c0 = (cid % 12) * 64;
#pragma unroll
  for (int j = 0; j < 8; ++j) {
    int u = j * 256 + t;
    int c = u >> 5, s4 = (u & 31) * 4;
    *(float4*)&tl[c][s4] =
        *(const float4*)(ctx + ((size_t)b * IDF + c0 + c) * SLN + s4);
  }
  __syncthreads();
#pragma unroll
  for (int j = 0; j < 8; ++j) {
    int u = j * 256 + t;
    int s = u >> 4, c4 = (u & 15) * 4;
    v4hf h;
#pragma unroll
    for (int e = 0; e < 4; ++e) h[e] = (_Float16)tl[c4 + e][s];
    *(v4hf*)(cTf + ((size_t)b * SLN + s) * IDF + c0 + c4) = h;
  }
}

// -----------------------------------------------------------------------------
// K1 proj: round-24 exact (BK=64, padded LDS [128][72], known-good).
// -----------------------------------------------------------------------------
__global__ __launch_bounds__(256) void proj_k(const _Float16* __restrict__ cTf,
                                              const _Float16* __restrict__ Wf,
                                              _Float16* __restrict__ STf,
                                              _Float16* __restrict__ Shvf) {
  const int b = blockIdx.y, o0 = blockIdx.x * 32;
  const int t = threadIdx.x, w = t >> 6, lane = t & 63;
  const int lr = lane & 15, lg = lane >> 4;
  const int ws = w >> 1, wq = w & 1;
  __shared__ _Float16 AL[128][72];

  v4f acc[4];
#pragma unroll
  for (int fr = 0; fr < 4; ++fr) acc[fr] = (v4f){0.f, 0.f, 0.f, 0.f};

  const int ra = t >> 1;
  const int cb = (t & 1) * 4;
  const _Float16* pA = cTf + ((size_t)b * SLN + ra) * IDF + cb * 8;
  const size_t wOff = (size_t)(o0 + wq * 16 + lr) * IDF + lg * 8;

  uint4 aS0, aS1, aS2, aS3, bS0, bS1, bS2, bS3;
  v8hf wc0, wc1, wn0, wn1;
  aS0 = *(const uint4*)(pA);
  aS1 = *(const uint4*)(pA + 8);
  aS2 = *(const uint4*)(pA + 16);
  aS3 = *(const uint4*)(pA + 24);
  bS0 = *(const uint4*)(pA + 64);
  bS1 = *(const uint4*)(pA + 72);
  bS2 = *(const uint4*)(pA + 80);
  bS3 = *(const uint4*)(pA + 88);
  wc0 = *(const v8hf*)(Wf + wOff);
  wc1 = *(const v8hf*)(Wf + wOff + 32);

#define PROJ_BODY(S0, S1, S2, S3, IT)                                          \
  {                                                                            \
    lbar();                                                                    \
    *(uint4*)&AL[ra][(cb + 0) * 8] = S0;                                       \
    *(uint4*)&AL[ra][(cb + 1) * 8] = S1;                                       \
    *(uint4*)&AL[ra][(cb + 2) * 8] = S2;                                       \
    *(uint4*)&AL[ra][(cb + 3) * 8] = S3;                                       \
    if ((IT) + 2 < NT2) {                                                      \
      S0 = *(const uint4*)(pA + ((IT) + 2) * 64);                              \
      S1 = *(const uint4*)(pA + ((IT) + 2) * 64 + 8);                          \
      S2 = *(const uint4*)(pA + ((IT) + 2) * 64 + 16);                         \
      S3 = *(const uint4*)(pA + ((IT) + 2) * 64 + 24);                         \
    }                                                                          \
    if ((IT) + 1 < NT2) {                                                      \
      wn0 = *(const v8hf*)(Wf + wOff + ((IT) + 1) * 64);                       \
      wn1 = *(const v8hf*)(Wf + wOff + ((IT) + 1) * 64 + 32);                  \
    }                                                                          \
    lbar();                                                                    \
    _Pragma("unroll") for (int fr = 0; fr < 4; ++fr) {                         \
      const int r = ws * 64 + fr * 16 + lr;                                    \
      v8hf ah0 = *(const v8hf*)&AL[r][lg * 8];                                 \
      acc[fr] = MFMAH(ah0, wc0, acc[fr], 0, 0, 0);                             \
      v8hf ah1 = *(const v8hf*)&AL[r][32 + lg * 8];                            \
      acc[fr] = MFMAH(ah1, wc1, acc[fr], 0, 0, 0);                             \
    }                                                                          \
    wc0 = wn0;                                                                 \
    wc1 = wn1;                                                                 \
  }

  for (int it2 = 0; it2 < NT2 / 2; ++it2) {
    const int itE = it2 * 2;
    PROJ_BODY(aS0, aS1, aS2, aS3, itE);
    PROJ_BODY(bS0, bS1, bS2, bS3, itE + 1);
  }
#undef PROJ_BODY

  const int o = o0 + wq * 16 + lr;
#pragma unroll
  for (int fr = 0; fr < 4; ++fr) {
    v4hf hp;
#pragma unroll
    for (int r = 0; r < 4; ++r) {
      int s = ws * 64 + fr * 16 + lg * 4 + r;
      _Float16 h = (_Float16)acc[fr][r];
      STf[((size_t)b * SLN + s) * IDF + o] = h;
      hp[r] = h;
    }
    *(v4hf*)(Shvf + ((size_t)b * IDF + o) * SLN + ws * 64 + fr * 16 + lg * 4) =
        hp;
  }
}

// -----------------------------------------------------------------------------
// K2 qkpv: round-26 + B bank-conflict fix. B chunk swizzle key now
// K(row) = (row&15) ^ ((row>>3)&3): folds row bits 3-4 into LOW chunk bits
// so the 4 lg-lanes of each b32 read hit 4 distinct banks (was 4-way same-
// bank). Applied on BOTH gload global source and LDS read (involution per
// row) -> values bit-identical. Everything else unchanged.
// -----------------------------------------------------------------------------
__global__ __launch_bounds__(256, 2) void qkpv_k(const float* __restrict__ input,
                                                 const _Float16* __restrict__ STf,
                                                 const _Float16* __restrict__ Shvf,
                                                 const int* __restrict__ mask,
                                                 float* __restrict__ wc,
                                                 float* __restrict__ attn_out) {
  const int bid = blockIdx.x;
  const int nid = (bid & 7) * 64 + (bid >> 3);  // XCD swizzle, 512 blocks
  const int b = nid >> 4, q0 = (nid & 15) * 64;
  const int t = threadIdx.x, w = t >> 6, lane = t & 63;
  const int lr = lane & 15, lg = lane >> 4;

  // LDS: bufA0 @0 (16K), bufB0 @16384 (16K), bufA1 @32768, bufB1 @49152,
  // msk @65536 (512B). Total 66048 B. PL (16 KB) overlays bufA0 after QK.
  __shared__ __align__(16) char lds[66048];
  float* const msk = (float*)(lds + 65536);
  char* const PLb = lds;

  if (t < SLN) msk[t] = -10000.0f * (float)mask[b * SLN + t];

  v4f acc[8];
#pragma unroll
  for (int fr = 0; fr < 8; ++fr) acc[fr] = (v4f){0.f, 0.f, 0.f, 0.f};

  // A staging: wave w stages ST rows [w*32,+32) x 64 k, 4 gloads,
  // chunk-XOR presource c' = c ^ (row&7).
  const int rAl = (lane >> 3);
  const int cpA = lane & 7;
  const _Float16* gA[4];
#pragma unroll
  for (int g = 0; g < 4; ++g) {
    const int row = w * 32 + g * 8 + rAl;
    const int c = cpA ^ (row & 7);
    gA[g] = STf + ((size_t)b * SLN + row) * IDF + c * 8;
  }
  const int dA = w * 4096;  // within A buffer

  // B staging: wave w stages input rows (k) [w*16,+16) x 64 q f32, 4 gloads.
  // chunk swizzle key K(row) = (row&15) ^ ((row>>3)&3).
  const float* gBp[4];
#pragma unroll
  for (int g = 0; g < 4; ++g) {
    const int row = w * 16 + g * 4 + (lane >> 4);
    const int K = (row & 15) ^ ((row >> 3) & 3);
    gBp[g] = input + ((size_t)b * IDF + row) * QLN + q0 + 4 * ((lane & 15) ^ K);
  }
  const int dB = w * 4096;  // within B buffer

  // prologue: t=0 (A x4, B x4), t=1 (A x4, B x4)  [per-wave FIFO order]
#pragma unroll
  for (int g = 0; g < 4; ++g) gload16(gA[g], lds + dA + g * 1024);
#pragma unroll
  for (int g = 0; g < 4; ++g) gload16(gBp[g], lds + 16384 + dB + g * 1024);
#pragma unroll
  for (int g = 0; g < 4; ++g) gload16(gA[g] + 64, lds + 32768 + dA + g * 1024);
#pragma unroll
  for (int g = 0; g < 4; ++g)
    gload16(gBp[g] + (size_t)64 * QLN, lds + 49152 + dB + g * 1024);

  const int qc = w * 4 + (lr >> 2);  // q>>2 within tile
  const int qw = lr & 3;             // q word within chunk

#define QK_WIN(AOFF, BOFF, IT, VMC)                                            \
  {                                                                            \
    asm volatile("s_waitcnt vmcnt(" #VMC ")" ::: "memory");                    \
    __builtin_amdgcn_sched_barrier(0);                                         \
    __builtin_amdgcn_s_barrier();                                              \
    __builtin_amdgcn_sched_barrier(0);                                         \
    const char* Ab = lds + (AOFF);                                             \
    const char* Bb = lds + (BOFF);                                             \
    v8hf bh[2];                                                                \
    _Pragma("unroll") for (int kk = 0; kk < 2; ++kk)                           \
        _Pragma("unroll") for (int e = 0; e < 8; ++e) {                        \
      const int row = kk * 32 + lg * 8 + e;                                    \
      const int K = (row & 15) ^ ((row >> 3) & 3);                             \
      const int ch = qc ^ K;                                                   \
      float v = *(const float*)(Bb + row * 256 + ch * 16 + qw * 4);            \
      bh[kk][e] = (_Float16)v;                                                 \
    }                                                                          \
    __builtin_amdgcn_s_setprio(1);                                             \
    _Pragma("unroll") for (int fr = 0; fr < 8; ++fr) {                         \
      const int r = fr * 16 + lr;                                              \
      _Pragma("unroll") for (int kk = 0; kk < 2; ++kk) {                       \
        const int cc = (kk * 4 + lg) ^ (r & 7);                                \
        v8hf ah = *(const v8hf*)(Ab + r * 128 + cc * 16);                      \
        acc[fr] = MFMAH(ah, bh[kk], acc[fr], 0, 0, 0);                         \
      }                                                                        \
    }                                                                          \
    __builtin_amdgcn_s_setprio(0);                                             \
    asm volatile("s_waitcnt lgkmcnt(0)" ::: "memory");                         \
    __builtin_amdgcn_s_barrier();                                              \
    if ((IT) + 2 < NT2) {                                                      \
      _Pragma("unroll") for (int g = 0; g < 4; ++g)                            \
          gload16(gA[g] + (size_t)((IT) + 2) * 64,                             \
                  lds + (AOFF) + dA + g * 1024);                               \
      _Pragma("unroll") for (int g = 0; g < 4; ++g)                            \
          gload16(gBp[g] + (size_t)((IT) + 2) * 64 * QLN,                      \
                  lds + (BOFF) + dB + g * 1024);                               \
    }                                                                          \
  }

  for (int it2 = 0; it2 < 5; ++it2) {
    const int itE = it2 * 2;
    QK_WIN(0, 16384, itE, 8);
    QK_WIN(32768, 49152, itE + 1, 8);
  }
  QK_WIN(0, 16384, 10, 8);
  QK_WIN(32768, 49152, 11, 0);
#undef QK_WIN

  // softmax over s=128 for q = q0 + w*16 + lr; pure shfl.
  const int qh = w * 16 + lr;
  float mx = -3.0e38f;
#pragma unroll
  for (int fr = 0; fr < 8; ++fr)
#pragma unroll
    for (int r = 0; r < 4; ++r) {
      acc[fr][r] += msk[fr * 16 + lg * 4 + r];
      mx = fmaxf(mx, acc[fr][r]);
    }
  mx = fmaxf(mx, __shfl_xor(mx, 16));
  mx = fmaxf(mx, __shfl_xor(mx, 32));
  float sum = 0.f;
#pragma unroll
  for (int fr = 0; fr < 8; ++fr)
#pragma unroll
    for (int r = 0; r < 4; ++r) {
      float e = __expf(acc[fr][r] - mx);
      acc[fr][r] = e;
      sum += e;
    }
  sum += __shfl_xor(sum, 16);
  sum += __shfl_xor(sum, 32);
  const float inv = 1.0f / sum;
  const int q = q0 + qh;
#pragma unroll
  for (int fr = 0; fr < 8; ++fr) {
    v4hf hp;
#pragma unroll
    for (int r = 0; r < 4; ++r) {
      float p = acc[fr][r] * inv;
      attn_out[((size_t)b * SLN + fr * 16 + lg * 4 + r) * QLN + q] = p;
      hp[r] = (_Float16)p;
    }
    const int g = (fr * 2 + (lg >> 1)) ^ lr;
    *(v4hf*)(PLb + qh * 256 + g * 16 + (lg & 1) * 8) = hp;
  }
  __syncthreads();

  // ---- PV: wave -> (qfp = (w&1)*2, islab = (w>>1)*384, 24 i-frags) ----
  const int qfp = (w & 1) * 2;
  const int islab = (w >> 1) * 384;
  v8hf pa0v[4], pa1v[4];
#pragma unroll
  for (int kt = 0; kt < 4; ++kt) {
    const int g0 = (kt * 4 + lg) ^ lr;
    pa0v[kt] = *(const v8hf*)(PLb + (qfp * 16 + lr) * 256 + g0 * 16);
    pa1v[kt] = *(const v8hf*)(PLb + ((qfp + 1) * 16 + lr) * 256 + g0 * 16);
  }
  const _Float16* pShv = Shvf + ((size_t)b * IDF + islab + lr) * SLN + lg * 8;
  float* pWc = wc + ((size_t)b * IDF + islab + lr) * QLN + q0;
#pragma unroll 2
  for (int ifr = 0; ifr < 24; ++ifr) {
    v4f a0 = (v4f){0.f, 0.f, 0.f, 0.f};
    v4f a1 = (v4f){0.f, 0.f, 0.f, 0.f};
#pragma unroll
    for (int kt = 0; kt < 4; ++kt) {
      v8hf bb = *(const v8hf*)(pShv + (size_t)(ifr * 16) * SLN + kt * 32);
      a0 = MFMAH(pa0v[kt], bb, a0, 0, 0, 0);
      a1 = MFMAH(pa1v[kt], bb, a1, 0, 0, 0);
    }
    *(float4*)(pWc + (size_t)(ifr * 16) * QLN + qfp * 16 + lg * 4) =
        make_float4(a0[0], a0[1], a0[2], a0[3]);
    *(float4*)(pWc + (size_t)(ifr * 16) * QLN + (qfp + 1) * 16 + lg * 4) =
        make_float4(a1[0], a1[1], a1[2], a1[3]);
  }
}

// -----------------------------------------------------------------------------
extern "C" void kernel_launch(void* const* d_in, const int* in_sizes, int n_in,
                              void* d_out, int out_size, void* d_ws, size_t ws_size,
                              hipStream_t stream) {
  const float* input   = (const float*)d_in[0];
  const float* context = (const float*)d_in[1];
  const int*   mask    = (const int*)d_in[2];
  const float* w_conv  = (const float*)d_in[3];

  float* out      = (float*)d_out;
  float* wc       = out;
  float* attn_out = out + (size_t)NB * IDF * QLN;

  // ws: STf | Shvf = 12,582,912 B (< 29.36 MB OK).
  // Scratch in wc output region (dead before PV): cTf | Wf.
  const size_t SE = (size_t)NB * SLN * IDF;  // 3,145,728
  _Float16* wsb = (_Float16*)d_ws;
  _Float16* STf  = wsb;
  _Float16* Shvf = STf + SE;
  _Float16* scr  = (_Float16*)wc;
  _Float16* cTf  = scr;
  _Float16* Wf   = cTf + SE;

  prep_k<<<960, 256, 0, stream>>>(w_conv, context, Wf, cTf);
  proj_k<<<dim3(24, NB), 256, 0, stream>>>(cTf, Wf, STf, Shvf);
  qkpv_k<<<512, 256, 0, stream>>>(input, STf, Shvf, mask, wc, attn_out);
}